// Round 1
// baseline (332.999 us; speedup 1.0000x reference)
//
#include <hip/hip_runtime.h>

// Conv2D: x (32,64,64,64) f32 NCHW, w (128,64,3,3) OIHW, bias (128), pad=1, stride=1
// out (32,128,64,64) f32.
//
// Round 1: correct LDS-tiled fp32 direct conv.
// Block tile: 32 co x 8 h x 64 w (one n). 256 threads = 4 waves.
//   lane (tid&63)  -> w position (coalesced global/LDS, stride-1)
//   wave (tid>>6)  -> co subgroup of 8 (weight LDS reads wave-uniform -> broadcast)
// Cin processed in chunks of 8.  LDS ~30 KB -> ~4 blocks/CU.
// Each thread accumulates 8 co x 8 h outputs in registers (64 VGPR acc).

#define CONV_N   32
#define CONV_CI  64
#define CONV_H   64
#define CONV_W   64
#define CONV_CO  128
#define CO_T     32     // co per block
#define H_T      8      // h rows per block
#define CI_CH    8      // ci chunk

__global__ __launch_bounds__(256, 4)
void conv2d_f32_tiled(const float* __restrict__ x,
                      const float* __restrict__ wgt,
                      const float* __restrict__ bias,
                      float* __restrict__ out)
{
    __shared__ float Xlds[CI_CH][H_T + 2][CONV_W + 2]; // 8*10*66*4 = 21120 B
    __shared__ float Wlds[CO_T][CI_CH * 9];            // 32*72*4   =  9216 B

    const int tid  = threadIdx.x;
    const int co0  = blockIdx.x * CO_T;
    const int h0   = blockIdx.y * H_T;
    const int n    = blockIdx.z;

    const int tco  = tid >> 6;   // 0..3 (wave id) -> co subgroup
    const int lane = tid & 63;   // w position

    float acc[8][8];
    #pragma unroll
    for (int i = 0; i < 8; ++i)
        #pragma unroll
        for (int j = 0; j < 8; ++j)
            acc[i][j] = 0.0f;

    for (int cc = 0; cc < CONV_CI / CI_CH; ++cc) {
        const int ci0 = cc * CI_CH;

        // ---- stage input tile (with zero padding at borders) ----
        for (int idx = tid; idx < CI_CH * (H_T + 2) * (CONV_W + 2); idx += 256) {
            const int ww = idx % (CONV_W + 2);
            const int t  = idx / (CONV_W + 2);
            const int hh = t % (H_T + 2);
            const int ci = t / (H_T + 2);
            const int gh = h0 + hh - 1;
            const int gw = ww - 1;
            float v = 0.0f;
            if ((unsigned)gh < (unsigned)CONV_H && (unsigned)gw < (unsigned)CONV_W)
                v = x[(((size_t)n * CONV_CI + ci0 + ci) * CONV_H + gh) * CONV_W + gw];
            Xlds[ci][hh][ww] = v;
        }

        // ---- stage weight tile (72 contiguous floats per co) ----
        for (int idx = tid; idx < CO_T * CI_CH * 9; idx += 256) {
            const int r  = idx % (CI_CH * 9);
            const int co = idx / (CI_CH * 9);
            Wlds[co][r] = wgt[(size_t)(co0 + co) * (CONV_CI * 9) + ci0 * 9 + r];
        }

        __syncthreads();

        // ---- compute ----
        for (int ci = 0; ci < CI_CH; ++ci) {
            #pragma unroll
            for (int kh = 0; kh < 3; ++kh) {
                #pragma unroll
                for (int kw = 0; kw < 3; ++kw) {
                    float wv[8];
                    #pragma unroll
                    for (int i = 0; i < 8; ++i)
                        wv[i] = Wlds[tco * 8 + i][ci * 9 + kh * 3 + kw]; // wave-uniform -> broadcast
                    #pragma unroll
                    for (int j = 0; j < 8; ++j) {
                        const float xv = Xlds[ci][j + kh][lane + kw];    // stride-1 across lanes
                        #pragma unroll
                        for (int i = 0; i < 8; ++i)
                            acc[i][j] = fmaf(wv[i], xv, acc[i][j]);
                    }
                }
            }
        }

        __syncthreads();
    }

    // ---- epilogue: bias + coalesced store ----
    #pragma unroll
    for (int i = 0; i < 8; ++i) {
        const int co = co0 + tco * 8 + i;
        const float b = bias[co];
        #pragma unroll
        for (int j = 0; j < 8; ++j) {
            out[(((size_t)n * CONV_CO + co) * CONV_H + (h0 + j)) * CONV_W + lane] =
                acc[i][j] + b;
        }
    }
}

extern "C" void kernel_launch(void* const* d_in, const int* in_sizes, int n_in,
                              void* d_out, int out_size, void* d_ws, size_t ws_size,
                              hipStream_t stream)
{
    const float* x    = (const float*)d_in[0];
    const float* wgt  = (const float*)d_in[1];
    const float* bias = (const float*)d_in[2];
    float* out        = (float*)d_out;

    dim3 grid(CONV_CO / CO_T, CONV_H / H_T, CONV_N); // (4, 8, 32) = 1024 blocks
    dim3 block(256);
    conv2d_f32_tiled<<<grid, block, 0, stream>>>(x, wgt, bias, out);
}

// Round 2
// 44.032 us; speedup vs baseline: 7.5626x; 7.5626x over previous
//
#include <hip/hip_runtime.h>

// Conv2D 3x3 pad=1: x (32,64,64,64) f32 NCHW, w (128,64,3,3) OIHW, bias(128), out (32,128,64,64) f32.
// Implicit GEMM via bf16 MFMA: M=co(128), N=spatial(32*64*64), K=ci*9 (576).
//   prep_x: NCHW f32 -> xT[n][h][w][ci] bf16 (ci contiguous)
//   prep_w: OIHW f32 -> wT[co][p*64+ci] bf16, p=kh*3+kw
//   conv_mfma: per block: 1 n, 8 h rows, 64 w, all 128 co. 512 thr = 8 waves (2M x 4N).
//     Wave tile 64co x 128sp, mfma_f32_16x16x32_bf16, XOR-swizzled LDS (T2),
//     W planes double-buffered with issue-early/write-late (T14).

typedef short short8 __attribute__((ext_vector_type(8)));
typedef float f32x4  __attribute__((ext_vector_type(4)));

static __device__ __forceinline__ unsigned short f2bf(float f) {
    unsigned int u = __float_as_uint(f);
    u = (u + 0x7FFFu + ((u >> 16) & 1u)) >> 16;   // RNE
    return (unsigned short)u;
}
static __device__ __forceinline__ unsigned int pk2(float lo, float hi) {
    return (unsigned int)f2bf(lo) | ((unsigned int)f2bf(hi) << 16);
}

// ---------------- prep_x: x[n][ci][h][w] f32 -> xT[n][h][w][ci] bf16 ----------------
__global__ __launch_bounds__(256)
void prep_x(const float* __restrict__ x, unsigned short* __restrict__ xT)
{
    __shared__ float T[64][65];
    const int h = blockIdx.x, n = blockIdx.y, tid = threadIdx.x;
    const size_t nbase = (size_t)n * 262144 + (size_t)h * 64;
    #pragma unroll
    for (int i = 0; i < 16; ++i) {
        int idx = tid + i * 256;           // ci*64 + w
        int ci = idx >> 6, w = idx & 63;
        T[ci][w] = x[nbase + (size_t)ci * 4096 + w];
    }
    __syncthreads();
    const int w = tid >> 2, cg = tid & 3;  // cg: ci group of 16
    unsigned int pk[8];
    #pragma unroll
    for (int k = 0; k < 8; ++k)
        pk[k] = pk2(T[cg * 16 + 2 * k][w], T[cg * 16 + 2 * k + 1][w]);
    unsigned short* dst = xT + (((size_t)n * 64 + h) * 64 + w) * 64 + cg * 16;
    uint4 a; a.x = pk[0]; a.y = pk[1]; a.z = pk[2]; a.w = pk[3];
    uint4 b; b.x = pk[4]; b.y = pk[5]; b.z = pk[6]; b.w = pk[7];
    *(uint4*)(dst)     = a;
    *(uint4*)(dst + 8) = b;
}

// ---------------- prep_w: w[co][ci][kh][kw] f32 -> wT[co][p*64+ci] bf16 ----------------
__global__ __launch_bounds__(256)
void prep_w(const float* __restrict__ w, unsigned short* __restrict__ wT)
{
    int t = blockIdx.x * 256 + threadIdx.x;
    if (t >= 128 * 576) return;
    int co = t / 576, r = t - co * 576;
    int p = r >> 6, ci = r & 63;
    wT[t] = f2bf(w[(size_t)(co * 64 + ci) * 9 + p]);
}

// ---------------- main MFMA conv ----------------
// LDS: Xlds 10*66*64 bf16 = 84480 B  (elem(h',w',ci) at (h'*66+w')*64 + (ci ^ ((w'&7)*8)))
//      Wlds 2 x 128*64 bf16 = 32768 B (elem(co,ci) at co*64 + (ci ^ ((co&7)*8)))
#define XLDS_BYTES 84480
#define WLDS_BYTES 16384
#define TOTAL_LDS  (XLDS_BYTES + 2 * WLDS_BYTES)

__global__ __launch_bounds__(512, 2)
void conv_mfma(const unsigned short* __restrict__ xT,
               const unsigned short* __restrict__ wT,
               const float* __restrict__ bias,
               float* __restrict__ out)
{
    extern __shared__ __align__(16) char lds[];
    char* Wl = lds + XLDS_BYTES;

    const int tid = threadIdx.x;
    const int h0  = blockIdx.x * 8;
    const int n   = blockIdx.y;
    const int wid = tid >> 6, lane = tid & 63;
    const int wm = wid >> 2, wn = wid & 3;       // 2 M-groups x 4 N-groups
    const int l15 = lane & 15, l4 = lane >> 4;   // l4 in 0..3

    // ---- stage X tile (once), swizzled ----
    {
        const unsigned short* xTn = xT + (size_t)n * 262144;
        for (int G = tid; G < 5280; G += 512) {     // 10*66*8 granules of 16B
            int hp = G / 528;
            int r  = G - hp * 528;
            int wp = r >> 3, g = r & 7;
            int gh = h0 + hp - 1, gw = wp - 1;
            uint4 v; v.x = v.y = v.z = v.w = 0u;
            if ((unsigned)gh < 64u && (unsigned)gw < 64u)
                v = *(const uint4*)(xTn + ((gh * 64 + gw) * 64 + g * 8));
            *(uint4*)(lds + ((hp * 66 + wp) * 64 + ((g ^ (wp & 7)) * 8)) * 2) = v;
        }
    }

    // ---- W staging helpers (2 granules per thread per plane) ----
    const int wco0 = tid >> 3, wg = tid & 7;     // granule 0: co=wco0, granule 1: co=wco0+64
    const int wds0 = (wco0 * 64 + ((wg ^ (wco0 & 7)) * 8)) * 2;
    const int wds1 = ((wco0 + 64) * 64 + ((wg ^ ((wco0 + 64) & 7)) * 8)) * 2;
    const unsigned short* wsrc0 = wT + wco0 * 576 + wg * 8;
    const unsigned short* wsrc1 = wT + (wco0 + 64) * 576 + wg * 8;

    // stage plane 0 into buf 0
    {
        uint4 a = *(const uint4*)(wsrc0);
        uint4 b = *(const uint4*)(wsrc1);
        *(uint4*)(Wl + wds0) = a;
        *(uint4*)(Wl + wds1) = b;
    }
    __syncthreads();

    f32x4 acc[4][8];
    #pragma unroll
    for (int mf = 0; mf < 4; ++mf)
        #pragma unroll
        for (int nf = 0; nf < 8; ++nf)
            acc[mf][nf] = (f32x4)0.0f;

    #pragma unroll
    for (int p = 0; p < 9; ++p) {
        const int kh = p / 3, kw = p - kh * 3;
        const int bufoff = (p & 1) * WLDS_BYTES;

        uint4 nw0, nw1;
        if (p < 8) {                                  // issue next plane loads early
            nw0 = *(const uint4*)(wsrc0 + (p + 1) * 64);
            nw1 = *(const uint4*)(wsrc1 + (p + 1) * 64);
        }

        #pragma unroll
        for (int ci0 = 0; ci0 < 64; ci0 += 32) {
            const int cg = ci0 >> 3;                  // 0 or 4
            short8 Af[4], Bf[8];
            #pragma unroll
            for (int mf = 0; mf < 4; ++mf) {
                const int co = wm * 64 + mf * 16 + l15;
                const int g  = (cg + l4) ^ (co & 7);
                Af[mf] = *(const short8*)(Wl + bufoff + co * 128 + g * 16);
            }
            #pragma unroll
            for (int nf = 0; nf < 8; ++nf) {
                const int hp = wn * 2 + (nf >> 2) + kh;
                const int wp = (nf & 3) * 16 + l15 + kw;
                const int g  = (cg + l4) ^ (wp & 7);
                Bf[nf] = *(const short8*)(lds + (hp * 66 + wp) * 128 + g * 16);
            }
            #pragma unroll
            for (int mf = 0; mf < 4; ++mf)
                #pragma unroll
                for (int nf = 0; nf < 8; ++nf)
                    acc[mf][nf] = __builtin_amdgcn_mfma_f32_16x16x32_bf16(
                        Af[mf], Bf[nf], acc[mf][nf], 0, 0, 0);
        }

        if (p < 8) {                                  // write next plane into other buf
            *(uint4*)(Wl + (bufoff ^ WLDS_BYTES) + wds0) = nw0;
            *(uint4*)(Wl + (bufoff ^ WLDS_BYTES) + wds1) = nw1;
        }
        __syncthreads();
    }

    // ---- epilogue: bias + store (C/D: col=lane&15, row=(lane>>4)*4+reg) ----
    #pragma unroll
    for (int mf = 0; mf < 4; ++mf) {
        #pragma unroll
        for (int reg = 0; reg < 4; ++reg) {
            const int co = wm * 64 + mf * 16 + l4 * 4 + reg;
            const float bv = bias[co];
            #pragma unroll
            for (int nf = 0; nf < 8; ++nf) {
                const int s = wn * 128 + nf * 16 + l15;
                const int h = h0 + (s >> 6);
                const int w = s & 63;
                out[(((size_t)n * 128 + co) * 64 + h) * 64 + w] = acc[mf][nf][reg] + bv;
            }
        }
    }
}

// ---------------- fp32 fallback (round-1 kernel) if ws too small ----------------
__global__ __launch_bounds__(256, 4)
void conv2d_f32_tiled(const float* __restrict__ x,
                      const float* __restrict__ wgt,
                      const float* __restrict__ bias,
                      float* __restrict__ out)
{
    __shared__ float Xlds[8][10][66];
    __shared__ float Wlds[32][72];
    const int tid = threadIdx.x;
    const int co0 = blockIdx.x * 32, h0 = blockIdx.y * 8, n = blockIdx.z;
    const int tco = tid >> 6, lane = tid & 63;
    float acc[8][8];
    #pragma unroll
    for (int i = 0; i < 8; ++i)
        #pragma unroll
        for (int j = 0; j < 8; ++j) acc[i][j] = 0.0f;
    for (int cc = 0; cc < 8; ++cc) {
        const int ci0 = cc * 8;
        for (int idx = tid; idx < 8 * 10 * 66; idx += 256) {
            const int ww = idx % 66, t = idx / 66, hh = t % 10, ci = t / 10;
            const int gh = h0 + hh - 1, gw = ww - 1;
            float v = 0.0f;
            if ((unsigned)gh < 64u && (unsigned)gw < 64u)
                v = x[(((size_t)n * 64 + ci0 + ci) * 64 + gh) * 64 + gw];
            Xlds[ci][hh][ww] = v;
        }
        for (int idx = tid; idx < 32 * 72; idx += 256) {
            const int r = idx % 72, co = idx / 72;
            Wlds[co][r] = wgt[(size_t)(co0 + co) * 576 + ci0 * 9 + r];
        }
        __syncthreads();
        for (int ci = 0; ci < 8; ++ci)
            #pragma unroll
            for (int kh = 0; kh < 3; ++kh)
                #pragma unroll
                for (int kw = 0; kw < 3; ++kw) {
                    float wv[8];
                    #pragma unroll
                    for (int i = 0; i < 8; ++i) wv[i] = Wlds[tco * 8 + i][ci * 9 + kh * 3 + kw];
                    #pragma unroll
                    for (int j = 0; j < 8; ++j) {
                        const float xv = Xlds[ci][j + kh][lane + kw];
                        #pragma unroll
                        for (int i = 0; i < 8; ++i) acc[i][j] = fmaf(wv[i], xv, acc[i][j]);
                    }
                }
        __syncthreads();
    }
    #pragma unroll
    for (int i = 0; i < 8; ++i) {
        const int co = co0 + tco * 8 + i;
        const float b = bias[co];
        #pragma unroll
        for (int j = 0; j < 8; ++j)
            out[(((size_t)n * 128 + co) * 64 + (h0 + j)) * 64 + lane] = acc[i][j] + b;
    }
}

extern "C" void kernel_launch(void* const* d_in, const int* in_sizes, int n_in,
                              void* d_out, int out_size, void* d_ws, size_t ws_size,
                              hipStream_t stream)
{
    const float* x    = (const float*)d_in[0];
    const float* wgt  = (const float*)d_in[1];
    const float* bias = (const float*)d_in[2];
    float* out        = (float*)d_out;

    const size_t XT_BYTES = (size_t)32 * 64 * 64 * 64 * 2;   // 33554432
    const size_t WT_BYTES = (size_t)128 * 576 * 2;           // 147456

    if (ws_size < XT_BYTES + WT_BYTES) {
        dim3 grid(4, 8, 32);
        conv2d_f32_tiled<<<grid, 256, 0, stream>>>(x, wgt, bias, out);
        return;
    }

    unsigned short* xT = (unsigned short*)d_ws;
    unsigned short* wT = (unsigned short*)((char*)d_ws + XT_BYTES);

    (void)hipFuncSetAttribute((const void*)conv_mfma,
                              hipFuncAttributeMaxDynamicSharedMemorySize, TOTAL_LDS);

    prep_x<<<dim3(64, 32), 256, 0, stream>>>(x, xT);
    prep_w<<<dim3((128 * 576 + 255) / 256), 256, 0, stream>>>(wgt, wT);
    conv_mfma<<<dim3(8, 32), 512, TOTAL_LDS, stream>>>(xT, wT, bias, out);
}